// Round 20
// baseline (534.947 us; speedup 1.0000x reference)
//
#include <hip/hip_runtime.h>
#include <hip/hip_bf16.h>

#define N_NODES 50000
#define N_EDGES 800000
#define H 64
#define ED 32
#define LAYERS 3
#define NGRAPH 256
#define OUTD 32
#define SCALE 0.125f
#define SCAN_NB ((N_NODES + 255) / 256)   // 196

// fused front-end block ranges
#define NB_INIT 12500
#define NB_TE   8
#define NB_HIST 3125
#define NB_GB   2
#define NB_FRONT (NB_INIT + NB_TE + NB_HIST + NB_GB)
#define NB_GEMM ((N_NODES + 63) / 64)     // 782

typedef __attribute__((ext_vector_type(16))) float f16v;
typedef unsigned short ushort_t;

// fp32 -> bf16 round-to-nearest-even
__device__ __forceinline__ unsigned f2bf(float f) {
    unsigned u = __float_as_uint(f);
    return (u + 0x7FFFu + ((u >> 16) & 1u)) >> 16;
}

// ---------------- fused front end: init_h | te | hist | gbounds ----------------
__global__ __launch_bounds__(256) void k_front(
    const int* __restrict__ x, const float* __restrict__ node_emb, float* __restrict__ h,
    const float* __restrict__ edge_emb, const float* __restrict__ We, float* __restrict__ te,
    const int* __restrict__ ei, int* __restrict__ deg,
    const int* __restrict__ batch, int* __restrict__ gs)
{
    int b = blockIdx.x, t = threadIdx.x;
    if (b < NB_INIT) {
        int i = b * 256 + t;
        int n = i >> 6, c = i & 63;
        h[i] = node_emb[x[n] * H + c];
    } else if (b < NB_INIT + NB_TE) {
        int i = (b - NB_INIT) * 256 + t;
        if (i < LAYERS * 10 * H) {
            int c = i & 63;
            int cat = (i >> 6) % 10;
            int l = i / (10 * H);
            float acc = 0.f;
            for (int d = 0; d < ED; d++)
                acc += edge_emb[cat * ED + d] * We[((size_t)l * ED + d) * H + c];
            te[i] = acc;
        }
    } else if (b < NB_INIT + NB_TE + NB_HIST) {
        int e = (b - NB_INIT - NB_TE) * 256 + t;
        atomicAdd(&deg[ei[N_EDGES + e]], 1);
    } else {
        int g = (b - NB_INIT - NB_TE - NB_HIST) * 256 + t;
        if (g <= NGRAPH) {
            int lo = 0, hi = N_NODES;
            while (lo < hi) {
                int mid = (lo + hi) >> 1;
                if (batch[mid] < g) lo = mid + 1; else hi = mid;
            }
            gs[g] = lo;
        }
    }
}

// ---------------- scans ----------------
__global__ __launch_bounds__(256) void k_scan1(const int* __restrict__ deg, int* __restrict__ bsum) {
    __shared__ int red[256];
    int t = threadIdx.x;
    int i = blockIdx.x * 256 + t;
    red[t] = (i < N_NODES) ? deg[i] : 0;
    __syncthreads();
    for (int s = 128; s > 0; s >>= 1) {
        if (t < s) red[t] += red[t + s];
        __syncthreads();
    }
    if (t == 0) bsum[blockIdx.x] = red[0];
}

__global__ __launch_bounds__(256) void k_scan23(const int* __restrict__ deg, const int* __restrict__ bsum,
                                                int* __restrict__ row_start, int* __restrict__ cursor) {
    __shared__ int part[256];
    int t = threadIdx.x;
    part[t] = (t < SCAN_NB) ? bsum[t] : 0;
    __syncthreads();
    for (int off = 1; off < 256; off <<= 1) {
        int add = (t >= off) ? part[t - off] : 0;
        __syncthreads();
        part[t] += add;
        __syncthreads();
    }
    int boff = (blockIdx.x == 0) ? 0 : part[blockIdx.x - 1];
    __syncthreads();
    int i = blockIdx.x * 256 + t;
    int v = (i < N_NODES) ? deg[i] : 0;
    part[t] = v;
    __syncthreads();
    for (int off = 1; off < 256; off <<= 1) {
        int add = (t >= off) ? part[t - off] : 0;
        __syncthreads();
        part[t] += add;
        __syncthreads();
    }
    if (i < N_NODES) {
        int excl = part[t] - v + boff;
        row_start[i] = excl;
        cursor[i] = excl;
    }
}

// ---------------- gemm body: wave = matrix, lane = col (fp32 h via s_load) ----------------
// weight column loaded via VOLATILE reads -> compiler cannot rematerialize, stays in VGPRs
__device__ __forceinline__ void gemm_store(int wvi, int lane, int n, float acc,
                                           ushort_t* __restrict__ qs16, unsigned* __restrict__ kv32)
{
    if (wvi == 0)      __builtin_nontemporal_store((ushort_t)f2bf(acc), qs16 + (size_t)n * 128 + lane);
    else if (wvi == 3) __builtin_nontemporal_store((ushort_t)f2bf(acc), qs16 + (size_t)n * 128 + 64 + lane);
    else if (wvi == 1) ((ushort_t*)kv32)[(((size_t)n << 6) + lane) * 2 + 1] = (ushort_t)f2bf(acc);
    else               ((ushort_t*)kv32)[(((size_t)n << 6) + lane) * 2 + 0] = (ushort_t)f2bf(acc);
}

__device__ __forceinline__ void gemm_body(
    int bid, const float* __restrict__ h,
    const float* __restrict__ Wq, const float* __restrict__ Wk,
    const float* __restrict__ Wv, const float* __restrict__ Wsk,
    const float* __restrict__ bq, const float* __restrict__ bk,
    const float* __restrict__ bv, const float* __restrict__ bsk,
    ushort_t* __restrict__ qs16, unsigned* __restrict__ kv32)
{
    int wvi = threadIdx.x >> 6, lane = threadIdx.x & 63;
    const float* Wm = (wvi == 0) ? Wq : (wvi == 1) ? Wk : (wvi == 2) ? Wv : Wsk;
    const float* bm = (wvi == 0) ? bq : (wvi == 1) ? bk : (wvi == 2) ? bv : bsk;
    const volatile float* Wmv = Wm;    // volatile: loads can't be rematerialized in-loop
    f16v w0, w1, w2, w3;
    #pragma unroll
    for (int i = 0; i < 16; i++) w0[i] = Wmv[i * H + lane];
    #pragma unroll
    for (int i = 0; i < 16; i++) w1[i] = Wmv[(16 + i) * H + lane];
    #pragma unroll
    for (int i = 0; i < 16; i++) w2[i] = Wmv[(32 + i) * H + lane];
    #pragma unroll
    for (int i = 0; i < 16; i++) w3[i] = Wmv[(48 + i) * H + lane];
    float bias = bm[lane];
    int base = bid * 64;
    int nEnd = min(base + 64, N_NODES);
    for (int n = base; n < nEnd; n++) {
        const float* hrow = h + (size_t)n * H;
        f16v h0, h1, h2, h3;
        asm volatile(
            "s_load_dwordx16 %0, %4, 0x0\n\t"
            "s_load_dwordx16 %1, %4, 0x40\n\t"
            "s_load_dwordx16 %2, %4, 0x80\n\t"
            "s_load_dwordx16 %3, %4, 0xc0\n\t"
            "s_waitcnt lgkmcnt(0)"
            : "=s"(h0), "=s"(h1), "=s"(h2), "=s"(h3)
            : "s"(hrow));
        float acc = bias;
        #pragma unroll
        for (int i = 0; i < 16; i++) acc = fmaf(h0[i], w0[i], acc);
        #pragma unroll
        for (int i = 0; i < 16; i++) acc = fmaf(h1[i], w1[i], acc);
        #pragma unroll
        for (int i = 0; i < 16; i++) acc = fmaf(h2[i], w2[i], acc);
        #pragma unroll
        for (int i = 0; i < 16; i++) acc = fmaf(h3[i], w3[i], acc);
        gemm_store(wvi, lane, n, acc, qs16, kv32);
    }
}

// layers 1,2: plain gemm
__global__ __launch_bounds__(256, 1) void k_gemm(
    const float* __restrict__ h,
    const float* __restrict__ Wq, const float* __restrict__ Wk,
    const float* __restrict__ Wv, const float* __restrict__ Wsk,
    const float* __restrict__ bq, const float* __restrict__ bk,
    const float* __restrict__ bv, const float* __restrict__ bsk,
    ushort_t* __restrict__ qs16, unsigned* __restrict__ kv32)
{
    gemm_body(blockIdx.x, h, Wq, Wk, Wv, Wsk, bq, bk, bv, bsk, qs16, kv32);
}

// layer 0: gemm blocks [0,NB_GEMM), scatter blocks [NB_GEMM, NB_GEMM+NB_HIST)
__global__ __launch_bounds__(256, 1) void k_gemm_scatter(
    const float* __restrict__ h,
    const float* __restrict__ Wq, const float* __restrict__ Wk,
    const float* __restrict__ Wv, const float* __restrict__ Wsk,
    const float* __restrict__ bq, const float* __restrict__ bk,
    const float* __restrict__ bv, const float* __restrict__ bsk,
    ushort_t* __restrict__ qs16, unsigned* __restrict__ kv32,
    const int* __restrict__ ei, const int* __restrict__ ea,
    int* __restrict__ cursor, int* __restrict__ packed)
{
    int b = blockIdx.x;
    if (b < NB_GEMM) {
        gemm_body(b, h, Wq, Wk, Wv, Wsk, bq, bk, bv, bsk, qs16, kv32);
    } else {
        int e = (b - NB_GEMM) * 256 + threadIdx.x;
        int src = ei[e], dst = ei[N_EDGES + e], cat = ea[e];
        int pos = atomicAdd(&cursor[dst], 1);
        __builtin_nontemporal_store(src | (cat << 16), packed + pos);
    }
}

// per-edge load bundle
struct EdgeLd { uint4 kv; float4 t; };
__device__ __forceinline__ EdgeLd edge_load(int pkt, const unsigned* __restrict__ kv32,
                                            const float* tel, int i16) {
    EdgeLd r;
    r.kv = *(const uint4*)(kv32 + ((size_t)(pkt & 0xFFFF) << 6) + (i16 << 2));
    r.t  = *(const float4*)(tel + ((pkt >> 16) << 6) + (i16 << 2));
    return r;
}
__device__ __forceinline__ float edge_dot(const EdgeLd& e, const float4& q4) {
    float p;
    p = (__uint_as_float(e.kv.x & 0xFFFF0000u) + e.t.x) * q4.x;
    p = fmaf(__uint_as_float(e.kv.y & 0xFFFF0000u) + e.t.y, q4.y, p);
    p = fmaf(__uint_as_float(e.kv.z & 0xFFFF0000u) + e.t.z, q4.z, p);
    p = fmaf(__uint_as_float(e.kv.w & 0xFFFF0000u) + e.t.w, q4.w, p);
    p += __shfl_xor(p, 1); p += __shfl_xor(p, 2);
    p += __shfl_xor(p, 4); p += __shfl_xor(p, 8);
    return p * SCALE;
}
__device__ __forceinline__ float4 edge_val(const EdgeLd& e) {
    float4 v;
    v.x = __uint_as_float(e.kv.x << 16) + e.t.x;
    v.y = __uint_as_float(e.kv.y << 16) + e.t.y;
    v.z = __uint_as_float(e.kv.z << 16) + e.t.z;
    v.w = __uint_as_float(e.kv.w << 16) + e.t.w;
    return v;
}

// ---------------- fused gather: one dst per 16-lane group (4 dsts/wave) -------------
__global__ __launch_bounds__(256) void k_agg(
    const int* __restrict__ row_start, const int* __restrict__ row_end,
    const int* __restrict__ packed,
    const ushort_t* __restrict__ qs16, const unsigned* __restrict__ kv32,
    const float* __restrict__ te, float* __restrict__ h,
    const float* __restrict__ gW, const float* __restrict__ gb, float* __restrict__ gate)
{
    __shared__ float tel[10 * 64];
    int t = threadIdx.x;
    int wave = t >> 6, lane = t & 63;
    int g = lane >> 4, i16 = lane & 15;
    int dst = blockIdx.x * 16 + wave * 4 + g;
    bool active = dst < N_NODES;
    int beg = 0, end = 0;
    uint2 qw = {0u, 0u};
    if (active) {
        beg = row_start[dst];
        end = row_end[dst];
        qw = *(const uint2*)(qs16 + (size_t)dst * 128 + (i16 << 2));
    }
    for (int i = t; i < 10 * 64; i += 256) tel[i] = te[i];
    __syncthreads();
    float4 q4;
    q4.x = __uint_as_float(qw.x << 16);
    q4.y = __uint_as_float(qw.x & 0xFFFF0000u);
    q4.z = __uint_as_float(qw.y << 16);
    q4.w = __uint_as_float(qw.y & 0xFFFF0000u);
    float m = -1e30f, l = 0.f;
    float4 acc = {0.f, 0.f, 0.f, 0.f};
    int e = beg;
    for (; e + 3 < end; e += 4) {
        int p0 = packed[e], p1 = packed[e + 1], p2 = packed[e + 2], p3 = packed[e + 3];
        EdgeLd e0 = edge_load(p0, kv32, tel, i16);
        EdgeLd e1 = edge_load(p1, kv32, tel, i16);
        EdgeLd e2 = edge_load(p2, kv32, tel, i16);
        EdgeLd e3 = edge_load(p3, kv32, tel, i16);
        float a0 = edge_dot(e0, q4), a1 = edge_dot(e1, q4);
        float a2 = edge_dot(e2, q4), a3 = edge_dot(e3, q4);
        float mn = fmaxf(m, fmaxf(fmaxf(a0, a1), fmaxf(a2, a3)));
        float corr = __expf(m - mn);
        float w0 = __expf(a0 - mn), w1 = __expf(a1 - mn);
        float w2 = __expf(a2 - mn), w3 = __expf(a3 - mn);
        float4 v0 = edge_val(e0), v1 = edge_val(e1), v2 = edge_val(e2), v3 = edge_val(e3);
        acc.x = fmaf(w0, v0.x, fmaf(w1, v1.x, fmaf(w2, v2.x, fmaf(w3, v3.x, acc.x * corr))));
        acc.y = fmaf(w0, v0.y, fmaf(w1, v1.y, fmaf(w2, v2.y, fmaf(w3, v3.y, acc.y * corr))));
        acc.z = fmaf(w0, v0.z, fmaf(w1, v1.z, fmaf(w2, v2.z, fmaf(w3, v3.z, acc.z * corr))));
        acc.w = fmaf(w0, v0.w, fmaf(w1, v1.w, fmaf(w2, v2.w, fmaf(w3, v3.w, acc.w * corr))));
        l = fmaf(l, corr, (w0 + w1) + (w2 + w3));
        m = mn;
    }
    for (; e < end; e++) {
        int pkt = packed[e];
        EdgeLd e0 = edge_load(pkt, kv32, tel, i16);
        float a = edge_dot(e0, q4);
        float mn = fmaxf(m, a);
        float corr = __expf(m - mn);
        float w = __expf(a - mn);
        float4 v4 = edge_val(e0);
        acc.x = fmaf(w, v4.x, acc.x * corr);
        acc.y = fmaf(w, v4.y, acc.y * corr);
        acc.z = fmaf(w, v4.z, acc.z * corr);
        acc.w = fmaf(w, v4.w, acc.w * corr);
        l = fmaf(l, corr, w);
        m = mn;
    }
    float inv = (l > 0.f) ? 1.f / l : 0.f;
    uint2 sw = {0u, 0u};
    if (active) sw = *(const uint2*)(qs16 + (size_t)dst * 128 + 64 + (i16 << 2));
    float4 s4;
    s4.x = __uint_as_float(sw.x << 16);
    s4.y = __uint_as_float(sw.x & 0xFFFF0000u);
    s4.z = __uint_as_float(sw.y << 16);
    s4.w = __uint_as_float(sw.y & 0xFFFF0000u);
    float4 hv;
    hv.x = fmaxf(acc.x * inv + s4.x, 0.f);
    hv.y = fmaxf(acc.y * inv + s4.y, 0.f);
    hv.z = fmaxf(acc.z * inv + s4.z, 0.f);
    hv.w = fmaxf(acc.w * inv + s4.w, 0.f);
    if (active) *(float4*)(h + (size_t)dst * H + (i16 << 2)) = hv;
    if (gW && active) {
        float4 g4 = *(const float4*)(gW + (i16 << 2));
        float p = hv.x * g4.x + hv.y * g4.y + hv.z * g4.z + hv.w * g4.w;
        p += __shfl_xor(p, 1); p += __shfl_xor(p, 2);
        p += __shfl_xor(p, 4); p += __shfl_xor(p, 8);
        if (i16 == 0) gate[dst] = p + gb[0];
    }
}

// ---------------- fused per-graph readout ----------------
__global__ __launch_bounds__(256) void k_readout2(
    const float* __restrict__ h, const float* __restrict__ oW,
    const float* __restrict__ ob, const float* __restrict__ gate,
    const int* __restrict__ gs, float* __restrict__ out)
{
    __shared__ float wls[H * OUTD];
    __shared__ float hs[8][H + 1];
    __shared__ float red[256];
    __shared__ float den_s[8];
    __shared__ float gmax_s, den_tot;
    int t = threadIdx.x;
    int g = blockIdx.x;
    for (int i = t; i < H * OUTD; i += 256) wls[i] = oW[i];
    int beg = gs[g], end = gs[g + 1];
    float mx = -INFINITY;
    for (int n = beg + t; n < end; n += 256) mx = fmaxf(mx, gate[n]);
    red[t] = mx;
    __syncthreads();
    for (int sft = 128; sft > 0; sft >>= 1) {
        if (t < sft) red[t] = fmaxf(red[t], red[t + sft]);
        __syncthreads();
    }
    if (t == 0) gmax_s = red[0];
    __syncthreads();
    float gm = gmax_s;
    int ln = t >> 5, o = t & 31;
    float acc = 0.f, den = 0.f;
    for (int n0 = beg; n0 < end; n0 += 8) {
        __syncthreads();
        for (int i = t; i < 8 * H; i += 256) {
            int r = i >> 6, c = i & 63;
            int n = n0 + r;
            hs[r][c] = (n < end) ? h[(size_t)n * H + c] : 0.f;
        }
        __syncthreads();
        int n = n0 + ln;
        if (n < end) {
            float wt = __expf(gate[n] - gm);
            float d0 = 0.f;
            #pragma unroll
            for (int i = 0; i < H; i++) d0 += hs[ln][i] * wls[i * OUTD + o];
            acc += wt * d0;
            if (o == 0) den += wt;
        }
    }
    __syncthreads();
    red[t] = acc;
    if (o == 0) den_s[ln] = den;
    __syncthreads();
    for (int sft = 4; sft >= 1; sft >>= 1) {
        if (ln < sft) red[t] += red[t + sft * 32];
        __syncthreads();
    }
    if (t == 0) {
        float dt = 0.f;
        #pragma unroll
        for (int i = 0; i < 8; i++) dt += den_s[i];
        den_tot = dt;
    }
    __syncthreads();
    if (ln == 0) {
        float dt = den_tot;
        out[g * OUTD + o] = (dt > 0.f) ? red[o] / dt + ob[o] : 0.f;
    }
}

extern "C" void kernel_launch(void* const* d_in, const int* in_sizes, int n_in,
                              void* d_out, int out_size, void* d_ws, size_t ws_size,
                              hipStream_t stream)
{
    const int* x        = (const int*)d_in[0];
    const int* ei       = (const int*)d_in[1];
    const int* ea       = (const int*)d_in[2];
    const int* batch    = (const int*)d_in[3];
    const float* node_emb = (const float*)d_in[4];
    const float* edge_emb = (const float*)d_in[5];
    const float* Wq    = (const float*)d_in[6];
    const float* Wk    = (const float*)d_in[7];
    const float* Wv    = (const float*)d_in[8];
    const float* We    = (const float*)d_in[9];
    const float* Wskip = (const float*)d_in[10];
    const float* bq    = (const float*)d_in[11];
    const float* bk    = (const float*)d_in[12];
    const float* bv    = (const float*)d_in[13];
    const float* bskip = (const float*)d_in[14];
    const float* gate_W = (const float*)d_in[15];
    const float* gate_b = (const float*)d_in[16];
    const float* out_W  = (const float*)d_in[17];
    const float* out_b  = (const float*)d_in[18];
    float* out = (float*)d_out;

    const size_t NH = (size_t)N_NODES * H;
    float* ws   = (float*)d_ws;
    float* h    = ws;                        // fp32 h, NH floats
    ushort_t* qs16 = (ushort_t*)(h + NH);    // bf16 [q(64)|s(64)] per node
    unsigned* kv32 = (unsigned*)(h + 2 * NH); // packed bf16 k|v, 64 uints/node
    float* te   = h + 3 * NH;
    float* gate = te + LAYERS * 10 * H;
    int* deg       = (int*)(gate + N_NODES);
    int* row_start = deg + N_NODES;
    int* cursor    = row_start + N_NODES;
    int* packed    = cursor + N_NODES;
    int* gs        = packed + N_EDGES;   // 257 ints
    int* bsum      = gs + NGRAPH + 1;    // 196

    hipMemsetAsync(deg, 0, N_NODES * sizeof(int), stream);

    k_front<<<NB_FRONT, 256, 0, stream>>>(x, node_emb, h, edge_emb, We, te, ei, deg, batch, gs);
    k_scan1<<<SCAN_NB, 256, 0, stream>>>(deg, bsum);
    k_scan23<<<SCAN_NB, 256, 0, stream>>>(deg, bsum, row_start, cursor);

    // layer 0: gemm fused with scatter (independent work, co-scheduled)
    k_gemm_scatter<<<NB_GEMM + NB_HIST, 256, 0, stream>>>(
        h, Wq, Wk, Wv, Wskip, bq, bk, bv, bskip, qs16, kv32, ei, ea, cursor, packed);
    k_agg<<<(N_NODES + 15) / 16, 256, 0, stream>>>(
        row_start, cursor, packed, qs16, kv32, te, h, nullptr, nullptr, nullptr);

    for (int l = 1; l < LAYERS; l++) {
        k_gemm<<<NB_GEMM, 256, 0, stream>>>(
            h,
            Wq + (size_t)l * H * H, Wk + (size_t)l * H * H,
            Wv + (size_t)l * H * H, Wskip + (size_t)l * H * H,
            bq + (size_t)l * H, bk + (size_t)l * H, bv + (size_t)l * H, bskip + (size_t)l * H,
            qs16, kv32);
        const float* gw = (l == LAYERS - 1) ? gate_W : nullptr;
        const float* gb = (l == LAYERS - 1) ? gate_b : nullptr;
        float* gp       = (l == LAYERS - 1) ? gate : nullptr;
        k_agg<<<(N_NODES + 15) / 16, 256, 0, stream>>>(
            row_start, cursor, packed, qs16, kv32, te + (size_t)l * 10 * H, h, gw, gb, gp);
    }

    k_readout2<<<NGRAPH, 256, 0, stream>>>(h, out_W, out_b, gate, gs, out);
}

// Round 21
// 375.211 us; speedup vs baseline: 1.4257x; 1.4257x over previous
//
#include <hip/hip_runtime.h>
#include <hip/hip_bf16.h>

#define N_NODES 50000
#define N_EDGES 800000
#define H 64
#define ED 32
#define LAYERS 3
#define NGRAPH 256
#define OUTD 32
#define SCALE 0.125f
#define SCAN_NB ((N_NODES + 255) / 256)   // 196

// fused front-end block ranges
#define NB_INIT 12500
#define NB_TE   8
#define NB_HIST 3125
#define NB_GB   2
#define NB_WB   192                        // 3*256*64 bf16 weight fragments / 256
#define NB_FRONT (NB_INIT + NB_TE + NB_HIST + NB_GB + NB_WB)
#define NB_GEMM ((N_NODES + 63) / 64)     // 782

typedef __attribute__((ext_vector_type(8))) short bf16x8;
typedef __attribute__((ext_vector_type(4))) float f32x4;
typedef unsigned short ushort_t;

// fp32 -> bf16 round-to-nearest-even
__device__ __forceinline__ unsigned f2bf(float f) {
    unsigned u = __float_as_uint(f);
    return (u + 0x7FFFu + ((u >> 16) & 1u)) >> 16;
}
__device__ __forceinline__ short bfs(float f) { return (short)f2bf(f); }

// ---------------- fused front end: init_h | te | hist | gbounds | weight-frags ---------
__global__ __launch_bounds__(256) void k_front(
    const int* __restrict__ x, const float* __restrict__ node_emb, float* __restrict__ h,
    const float* __restrict__ edge_emb, const float* __restrict__ We, float* __restrict__ te,
    const int* __restrict__ ei, int* __restrict__ deg,
    const int* __restrict__ batch, int* __restrict__ gs,
    const float* __restrict__ Wq, const float* __restrict__ Wk,
    const float* __restrict__ Wv, const float* __restrict__ Wsk,
    ushort_t* __restrict__ wb16)
{
    int b = blockIdx.x, t = threadIdx.x;
    if (b < NB_INIT) {
        int i = b * 256 + t;
        int n = i >> 6, c = i & 63;
        h[i] = node_emb[x[n] * H + c];
    } else if (b < NB_INIT + NB_TE) {
        int i = (b - NB_INIT) * 256 + t;
        if (i < LAYERS * 10 * H) {
            int c = i & 63;
            int cat = (i >> 6) % 10;
            int l = i / (10 * H);
            float acc = 0.f;
            for (int d = 0; d < ED; d++)
                acc += edge_emb[cat * ED + d] * We[((size_t)l * ED + d) * H + c];
            te[i] = acc;
        }
    } else if (b < NB_INIT + NB_TE + NB_HIST) {
        int e = (b - NB_INIT - NB_TE) * 256 + t;
        atomicAdd(&deg[ei[N_EDGES + e]], 1);
    } else if (b < NB_INIT + NB_TE + NB_HIST + NB_GB) {
        int g = (b - NB_INIT - NB_TE - NB_HIST) * 256 + t;
        if (g <= NGRAPH) {
            int lo = 0, hi = N_NODES;
            while (lo < hi) {
                int mid = (lo + hi) >> 1;
                if (batch[mid] < g) lo = mid + 1; else hi = mid;
            }
            gs[g] = lo;
        }
    } else {
        // bf16 B-fragment layout: wb16[l][c][k], k contiguous (c = mat*64+n)
        int j = (b - NB_INIT - NB_TE - NB_HIST - NB_GB) * 256 + t;   // < 49152
        int c = j & 255;
        int k = (j >> 8) & 63;
        int l = j >> 14;
        int mat = c >> 6, n = c & 63;
        const float* Wm = (mat == 0) ? Wq : (mat == 1) ? Wk : (mat == 2) ? Wv : Wsk;
        float v = Wm[(size_t)l * 4096 + k * 64 + n];
        wb16[(size_t)l * 16384 + (size_t)c * 64 + k] = (ushort_t)f2bf(v);
    }
}

// ---------------- scans ----------------
__global__ __launch_bounds__(256) void k_scan1(const int* __restrict__ deg, int* __restrict__ bsum) {
    __shared__ int red[256];
    int t = threadIdx.x;
    int i = blockIdx.x * 256 + t;
    red[t] = (i < N_NODES) ? deg[i] : 0;
    __syncthreads();
    for (int s = 128; s > 0; s >>= 1) {
        if (t < s) red[t] += red[t + s];
        __syncthreads();
    }
    if (t == 0) bsum[blockIdx.x] = red[0];
}

__global__ __launch_bounds__(256) void k_scan23(const int* __restrict__ deg, const int* __restrict__ bsum,
                                                int* __restrict__ row_start, int* __restrict__ cursor) {
    __shared__ int part[256];
    int t = threadIdx.x;
    part[t] = (t < SCAN_NB) ? bsum[t] : 0;
    __syncthreads();
    for (int off = 1; off < 256; off <<= 1) {
        int add = (t >= off) ? part[t - off] : 0;
        __syncthreads();
        part[t] += add;
        __syncthreads();
    }
    int boff = (blockIdx.x == 0) ? 0 : part[blockIdx.x - 1];
    __syncthreads();
    int i = blockIdx.x * 256 + t;
    int v = (i < N_NODES) ? deg[i] : 0;
    part[t] = v;
    __syncthreads();
    for (int off = 1; off < 256; off <<= 1) {
        int add = (t >= off) ? part[t - off] : 0;
        __syncthreads();
        part[t] += add;
        __syncthreads();
    }
    if (i < N_NODES) {
        int excl = part[t] - v + boff;
        row_start[i] = excl;
        cursor[i] = excl;
    }
}

// ---------------- MFMA gemm body: wave = 16 nodes x 256 outputs ----------------
// A[m=lane&15][k=quad*8+j] from fp32 h (cvt); B[n=lane&15][k=quad*8+j] from wb16;
// C/D: col=lane&15, row=quad*4+reg. q|s and v|k packed into dwords.
__device__ __forceinline__ void gemm_mfma_body(
    int bid, const float* __restrict__ h, const ushort_t* __restrict__ wb,
    const float* __restrict__ bq, const float* __restrict__ bk,
    const float* __restrict__ bv, const float* __restrict__ bsk,
    unsigned* __restrict__ qs32, unsigned* __restrict__ kv32)
{
    int tid = threadIdx.x;
    int w = tid >> 6, lane = tid & 63;
    int n16 = lane & 15, quad = lane >> 4;
    int base = bid * 64;
    int nodeA = base + w * 16 + n16;
    const float* hrow = h + (size_t)min(nodeA, N_NODES - 1) * H;
    f32x4 acc[16];
    #pragma unroll
    for (int i = 0; i < 16; i++) acc[i] = (f32x4){0.f, 0.f, 0.f, 0.f};
    #pragma unroll
    for (int kb = 0; kb < 2; kb++) {
        const float* hp = hrow + kb * 32 + quad * 8;
        float4 ha = *(const float4*)hp;
        float4 hb = *(const float4*)(hp + 4);
        bf16x8 afr;
        afr[0] = bfs(ha.x); afr[1] = bfs(ha.y); afr[2] = bfs(ha.z); afr[3] = bfs(ha.w);
        afr[4] = bfs(hb.x); afr[5] = bfs(hb.y); afr[6] = bfs(hb.z); afr[7] = bfs(hb.w);
        #pragma unroll
        for (int ct = 0; ct < 16; ct++) {
            const bf16x8* bp = (const bf16x8*)(wb + ((size_t)(ct * 16 + n16)) * 64 + kb * 32 + quad * 8);
            acc[ct] = __builtin_amdgcn_mfma_f32_16x16x32_bf16(afr, *bp, acc[ct], 0, 0, 0);
        }
    }
    #pragma unroll
    for (int cc = 0; cc < 4; cc++) {
        int col = cc * 16 + n16;
        float bQ = bq[col], bK = bk[col], bV = bv[col], bS = bsk[col];
        #pragma unroll
        for (int r = 0; r < 4; r++) {
            int node = base + w * 16 + quad * 4 + r;
            if (node < N_NODES) {
                float qv = acc[cc][r] + bQ;
                float kk = acc[4 + cc][r] + bK;
                float vv = acc[8 + cc][r] + bV;
                float sv = acc[12 + cc][r] + bS;
                qs32[(size_t)node * 64 + col] = f2bf(qv) | (f2bf(sv) << 16);
                kv32[(size_t)node * 64 + col] = f2bf(vv) | (f2bf(kk) << 16);
            }
        }
    }
}

// layers 1,2: plain gemm
__global__ __launch_bounds__(256, 1) void k_gemm(
    const float* __restrict__ h, const ushort_t* __restrict__ wb,
    const float* __restrict__ bq, const float* __restrict__ bk,
    const float* __restrict__ bv, const float* __restrict__ bsk,
    unsigned* __restrict__ qs32, unsigned* __restrict__ kv32)
{
    gemm_mfma_body(blockIdx.x, h, wb, bq, bk, bv, bsk, qs32, kv32);
}

// layer 0: gemm blocks [0,NB_GEMM), scatter blocks [NB_GEMM, NB_GEMM+NB_HIST)
__global__ __launch_bounds__(256, 1) void k_gemm_scatter(
    const float* __restrict__ h, const ushort_t* __restrict__ wb,
    const float* __restrict__ bq, const float* __restrict__ bk,
    const float* __restrict__ bv, const float* __restrict__ bsk,
    unsigned* __restrict__ qs32, unsigned* __restrict__ kv32,
    const int* __restrict__ ei, const int* __restrict__ ea,
    int* __restrict__ cursor, int* __restrict__ packed)
{
    int b = blockIdx.x;
    if (b < NB_GEMM) {
        gemm_mfma_body(b, h, wb, bq, bk, bv, bsk, qs32, kv32);
    } else {
        int e = (b - NB_GEMM) * 256 + threadIdx.x;
        int src = ei[e], dst = ei[N_EDGES + e], cat = ea[e];
        int pos = atomicAdd(&cursor[dst], 1);
        packed[pos] = src | (cat << 16);
    }
}

// per-edge load bundle
struct EdgeLd { uint4 kv; float4 t; };
__device__ __forceinline__ EdgeLd edge_load(int pkt, const unsigned* __restrict__ kv32,
                                            const float* tel, int i16) {
    EdgeLd r;
    r.kv = *(const uint4*)(kv32 + ((size_t)(pkt & 0xFFFF) << 6) + (i16 << 2));
    r.t  = *(const float4*)(tel + ((pkt >> 16) << 6) + (i16 << 2));
    return r;
}
__device__ __forceinline__ float edge_dot(const EdgeLd& e, const float4& q4) {
    float p;
    p = (__uint_as_float(e.kv.x & 0xFFFF0000u) + e.t.x) * q4.x;
    p = fmaf(__uint_as_float(e.kv.y & 0xFFFF0000u) + e.t.y, q4.y, p);
    p = fmaf(__uint_as_float(e.kv.z & 0xFFFF0000u) + e.t.z, q4.z, p);
    p = fmaf(__uint_as_float(e.kv.w & 0xFFFF0000u) + e.t.w, q4.w, p);
    p += __shfl_xor(p, 1); p += __shfl_xor(p, 2);
    p += __shfl_xor(p, 4); p += __shfl_xor(p, 8);
    return p * SCALE;
}
__device__ __forceinline__ float4 edge_val(const EdgeLd& e) {
    float4 v;
    v.x = __uint_as_float(e.kv.x << 16) + e.t.x;
    v.y = __uint_as_float(e.kv.y << 16) + e.t.y;
    v.z = __uint_as_float(e.kv.z << 16) + e.t.z;
    v.w = __uint_as_float(e.kv.w << 16) + e.t.w;
    return v;
}

// ---------------- fused gather: one dst per 16-lane group (4 dsts/wave) -------------
__global__ __launch_bounds__(256) void k_agg(
    const int* __restrict__ row_start, const int* __restrict__ row_end,
    const int* __restrict__ packed,
    const unsigned* __restrict__ qs32, const unsigned* __restrict__ kv32,
    const float* __restrict__ te, float* __restrict__ h,
    const float* __restrict__ gW, const float* __restrict__ gb, float* __restrict__ gate)
{
    __shared__ float tel[10 * 64];
    int t = threadIdx.x;
    int wave = t >> 6, lane = t & 63;
    int g = lane >> 4, i16 = lane & 15;
    int dst = blockIdx.x * 16 + wave * 4 + g;
    bool active = dst < N_NODES;
    int beg = 0, end = 0;
    uint4 uq = {0u, 0u, 0u, 0u};
    if (active) {
        beg = row_start[dst];
        end = row_end[dst];
        uq = *(const uint4*)(qs32 + (size_t)dst * 64 + (i16 << 2));   // q lo16 | s hi16, x4 channels
    }
    for (int i = t; i < 10 * 64; i += 256) tel[i] = te[i];
    __syncthreads();
    float4 q4, s4;
    q4.x = __uint_as_float(uq.x << 16); s4.x = __uint_as_float(uq.x & 0xFFFF0000u);
    q4.y = __uint_as_float(uq.y << 16); s4.y = __uint_as_float(uq.y & 0xFFFF0000u);
    q4.z = __uint_as_float(uq.z << 16); s4.z = __uint_as_float(uq.z & 0xFFFF0000u);
    q4.w = __uint_as_float(uq.w << 16); s4.w = __uint_as_float(uq.w & 0xFFFF0000u);
    float m = -1e30f, l = 0.f;
    float4 acc = {0.f, 0.f, 0.f, 0.f};
    int e = beg;
    for (; e + 3 < end; e += 4) {
        int p0 = packed[e], p1 = packed[e + 1], p2 = packed[e + 2], p3 = packed[e + 3];
        EdgeLd e0 = edge_load(p0, kv32, tel, i16);
        EdgeLd e1 = edge_load(p1, kv32, tel, i16);
        EdgeLd e2 = edge_load(p2, kv32, tel, i16);
        EdgeLd e3 = edge_load(p3, kv32, tel, i16);
        float a0 = edge_dot(e0, q4), a1 = edge_dot(e1, q4);
        float a2 = edge_dot(e2, q4), a3 = edge_dot(e3, q4);
        float mn = fmaxf(m, fmaxf(fmaxf(a0, a1), fmaxf(a2, a3)));
        float corr = __expf(m - mn);
        float w0 = __expf(a0 - mn), w1 = __expf(a1 - mn);
        float w2 = __expf(a2 - mn), w3 = __expf(a3 - mn);
        float4 v0 = edge_val(e0), v1 = edge_val(e1), v2 = edge_val(e2), v3 = edge_val(e3);
        acc.x = fmaf(w0, v0.x, fmaf(w1, v1.x, fmaf(w2, v2.x, fmaf(w3, v3.x, acc.x * corr))));
        acc.y = fmaf(w0, v0.y, fmaf(w1, v1.y, fmaf(w2, v2.y, fmaf(w3, v3.y, acc.y * corr))));
        acc.z = fmaf(w0, v0.z, fmaf(w1, v1.z, fmaf(w2, v2.z, fmaf(w3, v3.z, acc.z * corr))));
        acc.w = fmaf(w0, v0.w, fmaf(w1, v1.w, fmaf(w2, v2.w, fmaf(w3, v3.w, acc.w * corr))));
        l = fmaf(l, corr, (w0 + w1) + (w2 + w3));
        m = mn;
    }
    for (; e < end; e++) {
        int pkt = packed[e];
        EdgeLd e0 = edge_load(pkt, kv32, tel, i16);
        float a = edge_dot(e0, q4);
        float mn = fmaxf(m, a);
        float corr = __expf(m - mn);
        float w = __expf(a - mn);
        float4 v4 = edge_val(e0);
        acc.x = fmaf(w, v4.x, acc.x * corr);
        acc.y = fmaf(w, v4.y, acc.y * corr);
        acc.z = fmaf(w, v4.z, acc.z * corr);
        acc.w = fmaf(w, v4.w, acc.w * corr);
        l = fmaf(l, corr, w);
        m = mn;
    }
    float inv = (l > 0.f) ? 1.f / l : 0.f;
    float4 hv;
    hv.x = fmaxf(acc.x * inv + s4.x, 0.f);
    hv.y = fmaxf(acc.y * inv + s4.y, 0.f);
    hv.z = fmaxf(acc.z * inv + s4.z, 0.f);
    hv.w = fmaxf(acc.w * inv + s4.w, 0.f);
    if (active) *(float4*)(h + (size_t)dst * H + (i16 << 2)) = hv;
    if (gW && active) {
        float4 g4 = *(const float4*)(gW + (i16 << 2));
        float p = hv.x * g4.x + hv.y * g4.y + hv.z * g4.z + hv.w * g4.w;
        p += __shfl_xor(p, 1); p += __shfl_xor(p, 2);
        p += __shfl_xor(p, 4); p += __shfl_xor(p, 8);
        if (i16 == 0) gate[dst] = p + gb[0];
    }
}

// ---------------- fused per-graph readout ----------------
__global__ __launch_bounds__(256) void k_readout2(
    const float* __restrict__ h, const float* __restrict__ oW,
    const float* __restrict__ ob, const float* __restrict__ gate,
    const int* __restrict__ gs, float* __restrict__ out)
{
    __shared__ float wls[H * OUTD];
    __shared__ float hs[8][H + 1];
    __shared__ float red[256];
    __shared__ float den_s[8];
    __shared__ float gmax_s, den_tot;
    int t = threadIdx.x;
    int g = blockIdx.x;
    for (int i = t; i < H * OUTD; i += 256) wls[i] = oW[i];
    int beg = gs[g], end = gs[g + 1];
    float mx = -INFINITY;
    for (int n = beg + t; n < end; n += 256) mx = fmaxf(mx, gate[n]);
    red[t] = mx;
    __syncthreads();
    for (int sft = 128; sft > 0; sft >>= 1) {
        if (t < sft) red[t] = fmaxf(red[t], red[t + sft]);
        __syncthreads();
    }
    if (t == 0) gmax_s = red[0];
    __syncthreads();
    float gm = gmax_s;
    int ln = t >> 5, o = t & 31;
    float acc = 0.f, den = 0.f;
    for (int n0 = beg; n0 < end; n0 += 8) {
        __syncthreads();
        for (int i = t; i < 8 * H; i += 256) {
            int r = i >> 6, c = i & 63;
            int n = n0 + r;
            hs[r][c] = (n < end) ? h[(size_t)n * H + c] : 0.f;
        }
        __syncthreads();
        int n = n0 + ln;
        if (n < end) {
            float wt = __expf(gate[n] - gm);
            float d0 = 0.f;
            #pragma unroll
            for (int i = 0; i < H; i++) d0 += hs[ln][i] * wls[i * OUTD + o];
            acc += wt * d0;
            if (o == 0) den += wt;
        }
    }
    __syncthreads();
    red[t] = acc;
    if (o == 0) den_s[ln] = den;
    __syncthreads();
    for (int sft = 4; sft >= 1; sft >>= 1) {
        if (ln < sft) red[t] += red[t + sft * 32];
        __syncthreads();
    }
    if (t == 0) {
        float dt = 0.f;
        #pragma unroll
        for (int i = 0; i < 8; i++) dt += den_s[i];
        den_tot = dt;
    }
    __syncthreads();
    if (ln == 0) {
        float dt = den_tot;
        out[g * OUTD + o] = (dt > 0.f) ? red[o] / dt + ob[o] : 0.f;
    }
}

extern "C" void kernel_launch(void* const* d_in, const int* in_sizes, int n_in,
                              void* d_out, int out_size, void* d_ws, size_t ws_size,
                              hipStream_t stream)
{
    const int* x        = (const int*)d_in[0];
    const int* ei       = (const int*)d_in[1];
    const int* ea       = (const int*)d_in[2];
    const int* batch    = (const int*)d_in[3];
    const float* node_emb = (const float*)d_in[4];
    const float* edge_emb = (const float*)d_in[5];
    const float* Wq    = (const float*)d_in[6];
    const float* Wk    = (const float*)d_in[7];
    const float* Wv    = (const float*)d_in[8];
    const float* We    = (const float*)d_in[9];
    const float* Wskip = (const float*)d_in[10];
    const float* bq    = (const float*)d_in[11];
    const float* bk    = (const float*)d_in[12];
    const float* bv    = (const float*)d_in[13];
    const float* bskip = (const float*)d_in[14];
    const float* gate_W = (const float*)d_in[15];
    const float* gate_b = (const float*)d_in[16];
    const float* out_W  = (const float*)d_in[17];
    const float* out_b  = (const float*)d_in[18];
    float* out = (float*)d_out;

    const size_t NH = (size_t)N_NODES * H;
    float* ws   = (float*)d_ws;
    float* h    = ws;                          // fp32 h, NH floats
    unsigned* qs32 = (unsigned*)(h + NH);      // q|s packed bf16, 64 dwords/node
    unsigned* kv32 = (unsigned*)(h + 2 * NH);  // v|k packed bf16, 64 dwords/node
    float* te   = h + 3 * NH;
    float* gate = te + LAYERS * 10 * H;
    int* deg       = (int*)(gate + N_NODES);
    int* row_start = deg + N_NODES;
    int* cursor    = row_start + N_NODES;
    int* packed    = cursor + N_NODES;
    int* gs        = packed + N_EDGES;   // 257 ints
    int* bsum      = gs + NGRAPH + 1;    // 196
    ushort_t* wb16 = (ushort_t*)(bsum + 256);  // 3*16384 bf16 weight fragments

    hipMemsetAsync(deg, 0, N_NODES * sizeof(int), stream);

    k_front<<<NB_FRONT, 256, 0, stream>>>(x, node_emb, h, edge_emb, We, te, ei, deg, batch, gs,
                                          Wq, Wk, Wv, Wskip, wb16);
    k_scan1<<<SCAN_NB, 256, 0, stream>>>(deg, bsum);
    k_scan23<<<SCAN_NB, 256, 0, stream>>>(deg, bsum, row_start, cursor);

    // layer 0: MFMA gemm fused with scatter (independent work, co-scheduled)
    k_gemm_scatter<<<NB_GEMM + NB_HIST, 256, 0, stream>>>(
        h, wb16, bq, bk, bv, bskip, qs32, kv32, ei, ea, cursor, packed);
    k_agg<<<(N_NODES + 15) / 16, 256, 0, stream>>>(
        row_start, cursor, packed, qs32, kv32, te, h, nullptr, nullptr, nullptr);

    for (int l = 1; l < LAYERS; l++) {
        k_gemm<<<NB_GEMM, 256, 0, stream>>>(
            h, wb16 + (size_t)l * 16384,
            bq + (size_t)l * H, bk + (size_t)l * H, bv + (size_t)l * H, bskip + (size_t)l * H,
            qs32, kv32);
        const float* gw = (l == LAYERS - 1) ? gate_W : nullptr;
        const float* gb = (l == LAYERS - 1) ? gate_b : nullptr;
        float* gp       = (l == LAYERS - 1) ? gate : nullptr;
        k_agg<<<(N_NODES + 15) / 16, 256, 0, stream>>>(
            row_start, cursor, packed, qs32, kv32, te + (size_t)l * 10 * H, h, gw, gb, gp);
    }

    k_readout2<<<NGRAPH, 256, 0, stream>>>(h, out_W, out_b, gate, gs, out);
}